// Round 13
// baseline (61.911 us; speedup 1.0000x reference)
//
#include <hip/hip_runtime.h>

// Problem constants (from reference)
#define NRB 512
#define NTK 1024
#define DD  64
#define GHH 128

// Dead dataflow: tgt = edge_index[1]+512 in [512,1536) but robot_msgs =
// agg[:512] -> all-zero => edge MLP + segment_sum dead. lrelu(x) =
// 0.55x + 0.45|x| factors score into a[n] + c[m] + sum_h wb[h]*|HR+HTB|.
//
// R13 = MEASUREMENT ROUND. R9 (22.58us) is best; models have failed to
// attribute ~12us for 5 rounds. This round launches prep 6x (idempotent,
// deterministic, same output) + score 1x:
//   dur_13 = 6(p+b) + s  vs  dur_9 = (p+b) + s  =>  p+b = (dur_13-22.58)/5.
// Kernel code below is byte-identical to R9 (the measured best).

// Workspace layout (floats):
//   HR    [512][128]     @ 0        (row-major)
//   HTBt4 [32][1024][4]  @ 65536    (h-interleaved transpose, incl bm1)
//   a     [512]          @ 196608
//   c     [1024]         @ 197120
//   wb    [128]          @ 198144   (0.45 * Wm2)

__global__ __launch_bounds__(256) void prep_kernel(
    const float* __restrict__ xr, const float* __restrict__ xt,
    const float* __restrict__ Wv1, const float* __restrict__ bv1,
    const float* __restrict__ Wv2, const float* __restrict__ bv2,
    const float* __restrict__ Wm1, const float* __restrict__ bm1,
    const float* __restrict__ Wm2, const float* __restrict__ bm2,
    float* __restrict__ HR, float* __restrict__ HTBt4,
    float* __restrict__ av, float* __restrict__ cv, float* __restrict__ wbv)
{
    const int t = threadIdx.x;   // 0..255
    const int b = blockIdx.x;    // 0..255
    const int i = t & 127;       // output neuron (column)
    const int g = t >> 7;        // row-group 0/1

    __shared__ float lds_w[128 * 132];   // row-major weights, stride 132
    __shared__ float xs[8 * 64];         // input rows (flat)
    __shared__ float sA[4 * 132];        // h1 (robot)
    __shared__ float sB[4 * 132];        // h  (robot)
    __shared__ float sT[8 * 132];        // task pre-transpose
    __shared__ float sR[8 * 132];        // reduction scratch

    float4* Lw = reinterpret_cast<float4*>(lds_w);

    if (b < 128) {
        // ================= robot path: rows r0..r0+3 =================
        const int r0 = b * 4;
        xs[t] = xr[r0 * DD + t];                     // 256 floats, coalesced

        // stage W1 = Wv1[:,128:192]: 2048 f4, 1 load + 1 store each
        {
            const float4* W = reinterpret_cast<const float4*>(Wv1);
            #pragma unroll
            for (int j = 0; j < 8; ++j) {
                const int e = t + 256 * j;           // 0..2047
                const int row = e >> 4, c4 = e & 15;
                Lw[row * 33 + c4] = W[row * 48 + 32 + c4];
            }
        }
        __syncthreads();

        // phase 1: h1 = lrelu(x @ W1^T + bv1), rows 2g,2g+1, col i
        {
            float a0 = bv1[i], a1 = a0;
            const float4* w4 = Lw + i * 33;
            const float4* x0 = reinterpret_cast<const float4*>(xs + (2*g)*64);
            const float4* x1 = reinterpret_cast<const float4*>(xs + (2*g+1)*64);
            #pragma unroll
            for (int k = 0; k < 16; ++k) {
                const float4 w = w4[k];
                const float4 p = x0[k];
                const float4 q = x1[k];
                a0 = fmaf(w.x, p.x, a0); a1 = fmaf(w.x, q.x, a1);
                a0 = fmaf(w.y, p.y, a0); a1 = fmaf(w.y, q.y, a1);
                a0 = fmaf(w.z, p.z, a0); a1 = fmaf(w.z, q.z, a1);
                a0 = fmaf(w.w, p.w, a0); a1 = fmaf(w.w, q.w, a1);
            }
            sA[(2*g)*132 + i]   = (a0 >= 0.f) ? a0 : 0.1f * a0;
            sA[(2*g+1)*132 + i] = (a1 >= 0.f) ? a1 : 0.1f * a1;
        }
        __syncthreads();

        // stage W2 = Wv2 [128][128]: 4096 f4
        {
            const float4* W = reinterpret_cast<const float4*>(Wv2);
            #pragma unroll
            for (int j = 0; j < 16; ++j) {
                const int e = t + 256 * j;           // 0..4095
                const int row = e >> 5, c4 = e & 31;
                Lw[row * 33 + c4] = W[row * 32 + c4];
            }
        }
        __syncthreads();

        // phase 2: h = h1 @ W2^T + bv2
        {
            float a0 = bv2[i], a1 = a0;
            const float4* w4 = Lw + i * 33;
            const float4* h0 = reinterpret_cast<const float4*>(sA + (2*g)*132);
            const float4* h1 = reinterpret_cast<const float4*>(sA + (2*g+1)*132);
            #pragma unroll 8
            for (int k = 0; k < 32; ++k) {
                const float4 w = w4[k];
                const float4 p = h0[k];
                const float4 q = h1[k];
                a0 = fmaf(w.x, p.x, a0); a1 = fmaf(w.x, q.x, a1);
                a0 = fmaf(w.y, p.y, a0); a1 = fmaf(w.y, q.y, a1);
                a0 = fmaf(w.z, p.z, a0); a1 = fmaf(w.z, q.z, a1);
                a0 = fmaf(w.w, p.w, a0); a1 = fmaf(w.w, q.w, a1);
            }
            sB[(2*g)*132 + i]   = a0;
            sB[(2*g+1)*132 + i] = a1;
        }
        __syncthreads();

        // stage W3 = Wm1[:, :128]: 4096 f4 (row stride 192 -> 48 f4)
        {
            const float4* W = reinterpret_cast<const float4*>(Wm1);
            #pragma unroll
            for (int j = 0; j < 16; ++j) {
                const int e = t + 256 * j;
                const int row = e >> 5, c4 = e & 31;
                Lw[row * 33 + c4] = W[row * 48 + c4];
            }
        }
        __syncthreads();

        // phase 3: hr = h @ W3^T; HR write + a-partials
        {
            const float wm2 = Wm2[i];
            float a0 = 0.f, a1 = 0.f;
            const float4* w4 = Lw + i * 33;
            const float4* h0 = reinterpret_cast<const float4*>(sB + (2*g)*132);
            const float4* h1 = reinterpret_cast<const float4*>(sB + (2*g+1)*132);
            #pragma unroll 8
            for (int k = 0; k < 32; ++k) {
                const float4 w = w4[k];
                const float4 p = h0[k];
                const float4 q = h1[k];
                a0 = fmaf(w.x, p.x, a0); a1 = fmaf(w.x, q.x, a1);
                a0 = fmaf(w.y, p.y, a0); a1 = fmaf(w.y, q.y, a1);
                a0 = fmaf(w.z, p.z, a0); a1 = fmaf(w.z, q.z, a1);
                a0 = fmaf(w.w, p.w, a0); a1 = fmaf(w.w, q.w, a1);
            }
            HR[(r0 + 2*g) * GHH + i]     = a0;       // coalesced
            HR[(r0 + 2*g + 1) * GHH + i] = a1;
            sR[(2*g)*132 + i]   = wm2 * a0;
            sR[(2*g+1)*132 + i] = wm2 * a1;
        }
        __syncthreads();

        // a[n] = 0.55 * sum_i sR[n][i];  one wave per row
        {
            const int row = t >> 6, c = t & 63;
            float s = sR[row*132 + c] + sR[row*132 + c + 64];
            #pragma unroll
            for (int off = 32; off >= 1; off >>= 1)
                s += __shfl_xor(s, off, 64);
            if (c == 0) av[r0 + row] = 0.55f * s;
        }
    } else {
        // ================= task path: tasks t0..t0+7 =================
        const int t0 = (b - 128) * 8;
        xs[t]       = xt[t0 * DD + t];
        xs[256 + t] = xt[t0 * DD + 256 + t];

        // stage Wt = Wm1[:,128:192]: 2048 f4
        {
            const float4* W = reinterpret_cast<const float4*>(Wm1);
            #pragma unroll
            for (int j = 0; j < 8; ++j) {
                const int e = t + 256 * j;
                const int row = e >> 4, c4 = e & 15;
                Lw[row * 33 + c4] = W[row * 48 + 32 + c4];
            }
        }
        __syncthreads();

        // rows 4g..4g+3: htb = x_task @ Wt^T + bm1
        {
            const float bb  = bm1[i];
            const float wm2 = Wm2[i];
            float a0 = bb, a1 = bb, a2 = bb, a3 = bb;
            const float4* w4 = Lw + i * 33;
            const float4* x0 = reinterpret_cast<const float4*>(xs + (4*g)*64);
            const float4* x1 = reinterpret_cast<const float4*>(xs + (4*g+1)*64);
            const float4* x2 = reinterpret_cast<const float4*>(xs + (4*g+2)*64);
            const float4* x3 = reinterpret_cast<const float4*>(xs + (4*g+3)*64);
            #pragma unroll
            for (int k = 0; k < 16; ++k) {
                const float4 w = w4[k];
                const float4 p0 = x0[k], p1 = x1[k], p2 = x2[k], p3 = x3[k];
                a0 = fmaf(w.x, p0.x, a0); a1 = fmaf(w.x, p1.x, a1);
                a2 = fmaf(w.x, p2.x, a2); a3 = fmaf(w.x, p3.x, a3);
                a0 = fmaf(w.y, p0.y, a0); a1 = fmaf(w.y, p1.y, a1);
                a2 = fmaf(w.y, p2.y, a2); a3 = fmaf(w.y, p3.y, a3);
                a0 = fmaf(w.z, p0.z, a0); a1 = fmaf(w.z, p1.z, a1);
                a2 = fmaf(w.z, p2.z, a2); a3 = fmaf(w.z, p3.z, a3);
                a0 = fmaf(w.w, p0.w, a0); a1 = fmaf(w.w, p1.w, a1);
                a2 = fmaf(w.w, p2.w, a2); a3 = fmaf(w.w, p3.w, a3);
            }
            sT[(4*g)*132 + i]   = a0;  sR[(4*g)*132 + i]   = wm2 * a0;
            sT[(4*g+1)*132 + i] = a1;  sR[(4*g+1)*132 + i] = wm2 * a1;
            sT[(4*g+2)*132 + i] = a2;  sR[(4*g+2)*132 + i] = wm2 * a2;
            sT[(4*g+3)*132 + i] = a3;  sR[(4*g+3)*132 + i] = wm2 * a3;
        }
        __syncthreads();

        // interleaved transposed write: HTBt4[h4][t0+tk] = htb[tk][4h4..4h4+3]
        {
            const int h4 = t >> 3, tk = t & 7;
            float4 v;
            v.x = sT[tk*132 + 4*h4 + 0];
            v.y = sT[tk*132 + 4*h4 + 1];
            v.z = sT[tk*132 + 4*h4 + 2];
            v.w = sT[tk*132 + 4*h4 + 3];
            reinterpret_cast<float4*>(HTBt4)[h4 * NTK + t0 + tk] = v;
        }

        // c[m] = 0.55 * sum_i sR[m][i] + bm2;  half-wave per task
        {
            const int row = t >> 5, c = t & 31;
            float s = sR[row*132 + c]      + sR[row*132 + c + 32]
                    + sR[row*132 + c + 64] + sR[row*132 + c + 96];
            #pragma unroll
            for (int off = 16; off >= 1; off >>= 1)
                s += __shfl_xor(s, off, 32);
            if (c == 0) cv[t0 + row] = 0.55f * s + bm2[0];
        }
        if (b == 128 && t < GHH) wbv[t] = 0.45f * Wm2[t];
    }
}

__global__ __launch_bounds__(1024) void score_softmax_kernel(
    const float* __restrict__ HR, const float* __restrict__ HTBt4,
    const float* __restrict__ av, const float* __restrict__ cv,
    const float* __restrict__ wbv, float* __restrict__ out)
{
    const int b   = blockIdx.x;     // 0..255
    const int tid = threadIdx.x;    // 0..1023 == m
    const int n0  = b * 2;

    const float4* tb  = reinterpret_cast<const float4*>(HTBt4) + tid;
    const float4* hrA = reinterpret_cast<const float4*>(HR + n0 * GHH);
    const float4* hrB = reinterpret_cast<const float4*>(HR + (n0 + 1) * GHH);
    const float4* wb4 = reinterpret_cast<const float4*>(wbv);

    float acc0 = 0.f, acc1 = 0.f;

    #pragma unroll 4
    for (int h4 = 0; h4 < 32; ++h4) {
        const float4 v  = tb[h4 << 10];     // coalesced dwordx4
        const float4 w  = wb4[h4];          // uniform
        const float4 r0 = hrA[h4];          // uniform
        const float4 r1 = hrB[h4];          // uniform
        acc0 = fmaf(w.x, fabsf(r0.x + v.x), acc0);
        acc1 = fmaf(w.x, fabsf(r1.x + v.x), acc1);
        acc0 = fmaf(w.y, fabsf(r0.y + v.y), acc0);
        acc1 = fmaf(w.y, fabsf(r1.y + v.y), acc1);
        acc0 = fmaf(w.z, fabsf(r0.z + v.z), acc0);
        acc1 = fmaf(w.z, fabsf(r1.z + v.z), acc1);
        acc0 = fmaf(w.w, fabsf(r0.w + v.w), acc0);
        acc1 = fmaf(w.w, fabsf(r1.w + v.w), acc1);
    }

    const float cm = cv[tid];
    float sc[2];
    sc[0] = acc0 + av[n0]     + cm;
    sc[1] = acc1 + av[n0 + 1] + cm;

    // ---- block-local softmax over the 1024 columns, both rows ----
    __shared__ float rmax[2][16], rsum[2][16];
    const int wid = tid >> 6, lane = tid & 63;

    #pragma unroll
    for (int n = 0; n < 2; ++n) {
        float mx = sc[n];
        #pragma unroll
        for (int off = 32; off >= 1; off >>= 1)
            mx = fmaxf(mx, __shfl_xor(mx, off, 64));
        if (lane == 0) rmax[n][wid] = mx;
    }
    __syncthreads();

    float ex[2];
    #pragma unroll
    for (int n = 0; n < 2; ++n) {
        float mx = rmax[n][0];
        #pragma unroll
        for (int k = 1; k < 16; ++k) mx = fmaxf(mx, rmax[n][k]);
        float e = expf(sc[n] - mx);
        ex[n] = e;
        float s = e;
        #pragma unroll
        for (int off = 32; off >= 1; off >>= 1) s += __shfl_xor(s, off, 64);
        if (lane == 0) rsum[n][wid] = s;
    }
    __syncthreads();

    #pragma unroll
    for (int n = 0; n < 2; ++n) {
        float s = rsum[n][0];
        #pragma unroll
        for (int k = 1; k < 16; ++k) s += rsum[n][k];
        out[(n0 + n) * NTK + tid] = ex[n] * (1.0f / s);
    }
}

extern "C" void kernel_launch(void* const* d_in, const int* in_sizes, int n_in,
                              void* d_out, int out_size, void* d_ws, size_t ws_size,
                              hipStream_t stream)
{
    const float* xr  = (const float*)d_in[0];
    const float* xt  = (const float*)d_in[1];
    // d_in[2]=edge_index, [3]=edge_attr, [4..7]=We1,be1,We2,be2 : provably dead
    const float* Wv1 = (const float*)d_in[8];
    const float* bv1 = (const float*)d_in[9];
    const float* Wv2 = (const float*)d_in[10];
    const float* bv2 = (const float*)d_in[11];
    const float* Wm1 = (const float*)d_in[12];
    const float* bm1 = (const float*)d_in[13];
    const float* Wm2 = (const float*)d_in[14];
    const float* bm2 = (const float*)d_in[15];

    float* ws    = (float*)d_ws;
    float* HR    = ws;
    float* HTBt4 = ws + 65536;
    float* av    = ws + 196608;
    float* cv    = ws + 197120;
    float* wbv   = ws + 198144;
    float* out   = (float*)d_out;

    // MEASUREMENT: prep x6 (idempotent; same output). dur = 6(p+b) + s.
    for (int rep = 0; rep < 6; ++rep) {
        hipLaunchKernelGGL(prep_kernel, dim3(256), dim3(256), 0, stream,
                           xr, xt, Wv1, bv1, Wv2, bv2, Wm1, bm1, Wm2, bm2,
                           HR, HTBt4, av, cv, wbv);
    }
    hipLaunchKernelGGL(score_softmax_kernel, dim3(256), dim3(1024), 0, stream,
                       HR, HTBt4, av, cv, wbv, out);
}

// Round 14
// 34.036 us; speedup vs baseline: 1.8190x; 1.8190x over previous
//
#include <hip/hip_runtime.h>

// Problem constants (from reference)
#define NRB 512
#define NTK 1024
#define DD  64
#define GHH 128

// Dead dataflow: tgt = edge_index[1]+512 in [512,1536) but robot_msgs =
// agg[:512] -> all-zero => edge MLP + segment_sum dead. lrelu(x) =
// 0.55x + 0.45|x| factors score into a[n] + c[m] + sum_h wb[h]*|HR+HTB|.
//
// R13 measurement: (prep + node-overhead) ~= 7.9us; score ~= 10-13us but
// invariant across 5 different instruction mixes => bound by the aggregate
// 128MB L2/XCD stream, not issue count. R14: Tn=4 score (128 blocks x 4 rows
// -> 64MB aggregate, same 512KB/CU stream, epilogue amortized); prep halves
// staging (64 robot blocks x 8 rows, 64 task blocks x 16 tasks).

// Workspace layout (floats):
//   HR    [512][128]     @ 0        (row-major)
//   HTBt4 [32][1024][4]  @ 65536    (h-interleaved transpose, incl bm1)
//   a     [512]          @ 196608
//   c     [1024]         @ 197120
//   wb    [128]          @ 198144   (0.45 * Wm2)

// ---------------------------------------------------------------------------
// Kernel A: prep. 128 blocks x 256 threads.
// Blocks 0..63: robot path, 8 robots -> HR rows + a[n].
// Blocks 64..127: task path, 16 tasks -> HTBt4 + c[m]; block 64 wb.
// lds_w[i][132] row-major (R9-validated); staged via coalesced global f4.
// ---------------------------------------------------------------------------
__global__ __launch_bounds__(256) void prep_kernel(
    const float* __restrict__ xr, const float* __restrict__ xt,
    const float* __restrict__ Wv1, const float* __restrict__ bv1,
    const float* __restrict__ Wv2, const float* __restrict__ bv2,
    const float* __restrict__ Wm1, const float* __restrict__ bm1,
    const float* __restrict__ Wm2, const float* __restrict__ bm2,
    float* __restrict__ HR, float* __restrict__ HTBt4,
    float* __restrict__ av, float* __restrict__ cv, float* __restrict__ wbv)
{
    const int t = threadIdx.x;   // 0..255
    const int b = blockIdx.x;    // 0..127
    const int i = t & 127;       // output neuron (column)
    const int g = t >> 7;        // thread-group 0/1

    __shared__ float lds_w[128 * 132];   // 66 KB weights, stride 132 (33 f4)
    __shared__ float xs[16 * 64];        // input rows (flat)
    __shared__ float sU[16 * 132];       // robot: sA(8)+sR(8); task: sT(16)
    __shared__ float sV[16 * 132];       // robot: sB(8);        task: sR(16)

    float4* Lw = reinterpret_cast<float4*>(lds_w);

    if (b < 64) {
        // ================= robot path: rows r0..r0+7 =================
        const int r0 = b * 8;
        xs[t]       = xr[r0 * DD + t];
        xs[256 + t] = xr[r0 * DD + 256 + t];

        float* sA = sU;              // 8 x 132
        float* sB = sV;              // 8 x 132
        float* sR = sU + 8 * 132;    // 8 x 132 (sA dead by then)

        // stage W1 = Wv1[:,128:192]: 2048 f4
        {
            const float4* W = reinterpret_cast<const float4*>(Wv1);
            #pragma unroll
            for (int j = 0; j < 8; ++j) {
                const int e = t + 256 * j;
                const int row = e >> 4, c4 = e & 15;
                Lw[row * 33 + c4] = W[row * 48 + 32 + c4];
            }
        }
        __syncthreads();

        // phase 1: h1 = lrelu(x @ W1^T + bv1), rows 4g..4g+3
        {
            const float bb = bv1[i];
            float a0 = bb, a1 = bb, a2 = bb, a3 = bb;
            const float4* w4 = Lw + i * 33;
            const float4* x0 = reinterpret_cast<const float4*>(xs + (4*g)*64);
            const float4* x1 = reinterpret_cast<const float4*>(xs + (4*g+1)*64);
            const float4* x2 = reinterpret_cast<const float4*>(xs + (4*g+2)*64);
            const float4* x3 = reinterpret_cast<const float4*>(xs + (4*g+3)*64);
            #pragma unroll
            for (int k = 0; k < 16; ++k) {
                const float4 w = w4[k];
                const float4 p0 = x0[k], p1 = x1[k], p2 = x2[k], p3 = x3[k];
                a0 = fmaf(w.x, p0.x, a0); a1 = fmaf(w.x, p1.x, a1);
                a2 = fmaf(w.x, p2.x, a2); a3 = fmaf(w.x, p3.x, a3);
                a0 = fmaf(w.y, p0.y, a0); a1 = fmaf(w.y, p1.y, a1);
                a2 = fmaf(w.y, p2.y, a2); a3 = fmaf(w.y, p3.y, a3);
                a0 = fmaf(w.z, p0.z, a0); a1 = fmaf(w.z, p1.z, a1);
                a2 = fmaf(w.z, p2.z, a2); a3 = fmaf(w.z, p3.z, a3);
                a0 = fmaf(w.w, p0.w, a0); a1 = fmaf(w.w, p1.w, a1);
                a2 = fmaf(w.w, p2.w, a2); a3 = fmaf(w.w, p3.w, a3);
            }
            sA[(4*g)*132 + i]   = (a0 >= 0.f) ? a0 : 0.1f * a0;
            sA[(4*g+1)*132 + i] = (a1 >= 0.f) ? a1 : 0.1f * a1;
            sA[(4*g+2)*132 + i] = (a2 >= 0.f) ? a2 : 0.1f * a2;
            sA[(4*g+3)*132 + i] = (a3 >= 0.f) ? a3 : 0.1f * a3;
        }
        __syncthreads();

        // stage W2 = Wv2 [128][128]: 4096 f4
        {
            const float4* W = reinterpret_cast<const float4*>(Wv2);
            #pragma unroll
            for (int j = 0; j < 16; ++j) {
                const int e = t + 256 * j;
                const int row = e >> 5, c4 = e & 31;
                Lw[row * 33 + c4] = W[row * 32 + c4];
            }
        }
        __syncthreads();

        // phase 2: h = h1 @ W2^T + bv2, rows 4g..4g+3
        {
            const float bb = bv2[i];
            float a0 = bb, a1 = bb, a2 = bb, a3 = bb;
            const float4* w4 = Lw + i * 33;
            const float4* h0 = reinterpret_cast<const float4*>(sA + (4*g)*132);
            const float4* h1 = reinterpret_cast<const float4*>(sA + (4*g+1)*132);
            const float4* h2 = reinterpret_cast<const float4*>(sA + (4*g+2)*132);
            const float4* h3 = reinterpret_cast<const float4*>(sA + (4*g+3)*132);
            #pragma unroll 8
            for (int k = 0; k < 32; ++k) {
                const float4 w = w4[k];
                const float4 p0 = h0[k], p1 = h1[k], p2 = h2[k], p3 = h3[k];
                a0 = fmaf(w.x, p0.x, a0); a1 = fmaf(w.x, p1.x, a1);
                a2 = fmaf(w.x, p2.x, a2); a3 = fmaf(w.x, p3.x, a3);
                a0 = fmaf(w.y, p0.y, a0); a1 = fmaf(w.y, p1.y, a1);
                a2 = fmaf(w.y, p2.y, a2); a3 = fmaf(w.y, p3.y, a3);
                a0 = fmaf(w.z, p0.z, a0); a1 = fmaf(w.z, p1.z, a1);
                a2 = fmaf(w.z, p2.z, a2); a3 = fmaf(w.z, p3.z, a3);
                a0 = fmaf(w.w, p0.w, a0); a1 = fmaf(w.w, p1.w, a1);
                a2 = fmaf(w.w, p2.w, a2); a3 = fmaf(w.w, p3.w, a3);
            }
            sB[(4*g)*132 + i]   = a0;
            sB[(4*g+1)*132 + i] = a1;
            sB[(4*g+2)*132 + i] = a2;
            sB[(4*g+3)*132 + i] = a3;
        }
        __syncthreads();

        // stage W3 = Wm1[:, :128]: 4096 f4
        {
            const float4* W = reinterpret_cast<const float4*>(Wm1);
            #pragma unroll
            for (int j = 0; j < 16; ++j) {
                const int e = t + 256 * j;
                const int row = e >> 5, c4 = e & 31;
                Lw[row * 33 + c4] = W[row * 48 + c4];
            }
        }
        __syncthreads();

        // phase 3: hr = h @ W3^T; HR write + a-partials, rows 4g..4g+3
        {
            const float wm2 = Wm2[i];
            float a0 = 0.f, a1 = 0.f, a2 = 0.f, a3 = 0.f;
            const float4* w4 = Lw + i * 33;
            const float4* h0 = reinterpret_cast<const float4*>(sB + (4*g)*132);
            const float4* h1 = reinterpret_cast<const float4*>(sB + (4*g+1)*132);
            const float4* h2 = reinterpret_cast<const float4*>(sB + (4*g+2)*132);
            const float4* h3 = reinterpret_cast<const float4*>(sB + (4*g+3)*132);
            #pragma unroll 8
            for (int k = 0; k < 32; ++k) {
                const float4 w = w4[k];
                const float4 p0 = h0[k], p1 = h1[k], p2 = h2[k], p3 = h3[k];
                a0 = fmaf(w.x, p0.x, a0); a1 = fmaf(w.x, p1.x, a1);
                a2 = fmaf(w.x, p2.x, a2); a3 = fmaf(w.x, p3.x, a3);
                a0 = fmaf(w.y, p0.y, a0); a1 = fmaf(w.y, p1.y, a1);
                a2 = fmaf(w.y, p2.y, a2); a3 = fmaf(w.y, p3.y, a3);
                a0 = fmaf(w.z, p0.z, a0); a1 = fmaf(w.z, p1.z, a1);
                a2 = fmaf(w.z, p2.z, a2); a3 = fmaf(w.z, p3.z, a3);
                a0 = fmaf(w.w, p0.w, a0); a1 = fmaf(w.w, p1.w, a1);
                a2 = fmaf(w.w, p2.w, a2); a3 = fmaf(w.w, p3.w, a3);
            }
            HR[(r0 + 4*g)     * GHH + i] = a0;
            HR[(r0 + 4*g + 1) * GHH + i] = a1;
            HR[(r0 + 4*g + 2) * GHH + i] = a2;
            HR[(r0 + 4*g + 3) * GHH + i] = a3;
            sR[(4*g)*132 + i]   = wm2 * a0;
            sR[(4*g+1)*132 + i] = wm2 * a1;
            sR[(4*g+2)*132 + i] = wm2 * a2;
            sR[(4*g+3)*132 + i] = wm2 * a3;
        }
        __syncthreads();

        // a[n] = 0.55 * sum_i sR[n][i];  8 rows x 32 lanes
        {
            const int row = t >> 5, c = t & 31;
            float s = sR[row*132 + c]      + sR[row*132 + c + 32]
                    + sR[row*132 + c + 64] + sR[row*132 + c + 96];
            #pragma unroll
            for (int off = 16; off >= 1; off >>= 1)
                s += __shfl_xor(s, off, 32);
            if (c == 0) av[r0 + row] = 0.55f * s;
        }
    } else {
        // ================= task path: tasks t0..t0+15 =================
        const int t0 = (b - 64) * 16;
        xs[t]       = xt[t0 * DD + t];
        xs[256 + t] = xt[t0 * DD + 256 + t];
        xs[512 + t] = xt[t0 * DD + 512 + t];
        xs[768 + t] = xt[t0 * DD + 768 + t];

        float* sT = sU;   // 16 x 132
        float* sR = sV;   // 16 x 132

        // stage Wt = Wm1[:,128:192]: 2048 f4
        {
            const float4* W = reinterpret_cast<const float4*>(Wm1);
            #pragma unroll
            for (int j = 0; j < 8; ++j) {
                const int e = t + 256 * j;
                const int row = e >> 4, c4 = e & 15;
                Lw[row * 33 + c4] = W[row * 48 + 32 + c4];
            }
        }
        __syncthreads();

        // tasks 8g..8g+7: htb = x_task @ Wt^T + bm1
        {
            const float bb  = bm1[i];
            const float wm2 = Wm2[i];
            float a0 = bb, a1 = bb, a2 = bb, a3 = bb;
            float a4 = bb, a5 = bb, a6 = bb, a7 = bb;
            const float4* w4 = Lw + i * 33;
            const float4* x0 = reinterpret_cast<const float4*>(xs + (8*g)*64);
            const float4* x1 = reinterpret_cast<const float4*>(xs + (8*g+1)*64);
            const float4* x2 = reinterpret_cast<const float4*>(xs + (8*g+2)*64);
            const float4* x3 = reinterpret_cast<const float4*>(xs + (8*g+3)*64);
            const float4* x4 = reinterpret_cast<const float4*>(xs + (8*g+4)*64);
            const float4* x5 = reinterpret_cast<const float4*>(xs + (8*g+5)*64);
            const float4* x6 = reinterpret_cast<const float4*>(xs + (8*g+6)*64);
            const float4* x7 = reinterpret_cast<const float4*>(xs + (8*g+7)*64);
            #pragma unroll
            for (int k = 0; k < 16; ++k) {
                const float4 w = w4[k];
                float4 p;
                p = x0[k];
                a0 = fmaf(w.x, p.x, a0); a0 = fmaf(w.y, p.y, a0);
                a0 = fmaf(w.z, p.z, a0); a0 = fmaf(w.w, p.w, a0);
                p = x1[k];
                a1 = fmaf(w.x, p.x, a1); a1 = fmaf(w.y, p.y, a1);
                a1 = fmaf(w.z, p.z, a1); a1 = fmaf(w.w, p.w, a1);
                p = x2[k];
                a2 = fmaf(w.x, p.x, a2); a2 = fmaf(w.y, p.y, a2);
                a2 = fmaf(w.z, p.z, a2); a2 = fmaf(w.w, p.w, a2);
                p = x3[k];
                a3 = fmaf(w.x, p.x, a3); a3 = fmaf(w.y, p.y, a3);
                a3 = fmaf(w.z, p.z, a3); a3 = fmaf(w.w, p.w, a3);
                p = x4[k];
                a4 = fmaf(w.x, p.x, a4); a4 = fmaf(w.y, p.y, a4);
                a4 = fmaf(w.z, p.z, a4); a4 = fmaf(w.w, p.w, a4);
                p = x5[k];
                a5 = fmaf(w.x, p.x, a5); a5 = fmaf(w.y, p.y, a5);
                a5 = fmaf(w.z, p.z, a5); a5 = fmaf(w.w, p.w, a5);
                p = x6[k];
                a6 = fmaf(w.x, p.x, a6); a6 = fmaf(w.y, p.y, a6);
                a6 = fmaf(w.z, p.z, a6); a6 = fmaf(w.w, p.w, a6);
                p = x7[k];
                a7 = fmaf(w.x, p.x, a7); a7 = fmaf(w.y, p.y, a7);
                a7 = fmaf(w.z, p.z, a7); a7 = fmaf(w.w, p.w, a7);
            }
            sT[(8*g)*132 + i]   = a0;  sR[(8*g)*132 + i]   = wm2 * a0;
            sT[(8*g+1)*132 + i] = a1;  sR[(8*g+1)*132 + i] = wm2 * a1;
            sT[(8*g+2)*132 + i] = a2;  sR[(8*g+2)*132 + i] = wm2 * a2;
            sT[(8*g+3)*132 + i] = a3;  sR[(8*g+3)*132 + i] = wm2 * a3;
            sT[(8*g+4)*132 + i] = a4;  sR[(8*g+4)*132 + i] = wm2 * a4;
            sT[(8*g+5)*132 + i] = a5;  sR[(8*g+5)*132 + i] = wm2 * a5;
            sT[(8*g+6)*132 + i] = a6;  sR[(8*g+6)*132 + i] = wm2 * a6;
            sT[(8*g+7)*132 + i] = a7;  sR[(8*g+7)*132 + i] = wm2 * a7;
        }
        __syncthreads();

        // interleaved transposed write: HTBt4[h4][t0+tk], 512 f4 per block
        #pragma unroll
        for (int j = 0; j < 2; ++j) {
            const int e  = t + 256 * j;      // 0..511
            const int h4 = e >> 4, tk = e & 15;
            float4 v;
            v.x = sT[tk*132 + 4*h4 + 0];
            v.y = sT[tk*132 + 4*h4 + 1];
            v.z = sT[tk*132 + 4*h4 + 2];
            v.w = sT[tk*132 + 4*h4 + 3];
            reinterpret_cast<float4*>(HTBt4)[h4 * NTK + t0 + tk] = v;
        }

        // c[m] = 0.55 * sum_i sR[m][i] + bm2;  16 rows x 16 lanes
        {
            const int row = t >> 4, c = t & 15;
            float s = 0.f;
            #pragma unroll
            for (int j = 0; j < 8; ++j) s += sR[row*132 + c + 16*j];
            #pragma unroll
            for (int off = 8; off >= 1; off >>= 1)
                s += __shfl_xor(s, off, 16);
            if (c == 0) cv[t0 + row] = 0.55f * s + bm2[0];
        }
        if (b == 64 && t < GHH) wbv[t] = 0.45f * Wm2[t];
    }
}

// ---------------------------------------------------------------------------
// Kernel B: fused score + softmax, Tn=4. 128 blocks x 1024 threads.
// Block b owns rows n0=4b..4b+3; thread tid owns column m=tid.
// hr(4 rows)+wb staged in 2.6KB LDS (b128 broadcasts). Per h4: ONE coalesced
// dwordx4 stream + 5 LDS broadcasts + 32 VALU. Aggregate HTBt4 traffic
// halves to 64MB vs Tn=2. Block softmax x4 rows, coalesced stores.
// ---------------------------------------------------------------------------
__global__ __launch_bounds__(1024) void score_softmax_kernel(
    const float* __restrict__ HR, const float* __restrict__ HTBt4,
    const float* __restrict__ av, const float* __restrict__ cv,
    const float* __restrict__ wbv, float* __restrict__ out)
{
    const int b   = blockIdx.x;     // 0..127
    const int tid = threadIdx.x;    // 0..1023 == m
    const int n0  = b * 4;

    __shared__ float s_hr[4 * GHH];   // rows n0..n0+3 (512 floats)
    __shared__ float s_wb[GHH];
    if (tid < 512)      s_hr[tid]       = HR[n0 * GHH + tid];
    else if (tid < 640) s_wb[tid - 512] = wbv[tid - 512];
    const float cm = cv[tid];
    __syncthreads();

    const float4* tb  = reinterpret_cast<const float4*>(HTBt4) + tid;
    const float4* hr4 = reinterpret_cast<const float4*>(s_hr);
    const float4* wb4 = reinterpret_cast<const float4*>(s_wb);

    float acc0 = 0.f, acc1 = 0.f, acc2 = 0.f, acc3 = 0.f;

    #pragma unroll 4
    for (int h4 = 0; h4 < 32; ++h4) {
        const float4 v  = tb[h4 << 10];     // coalesced dwordx4 stream
        const float4 w  = wb4[h4];          // LDS broadcasts
        const float4 r0 = hr4[h4];
        const float4 r1 = hr4[32 + h4];
        const float4 r2 = hr4[64 + h4];
        const float4 r3 = hr4[96 + h4];
        acc0 = fmaf(w.x, fabsf(r0.x + v.x), acc0);
        acc1 = fmaf(w.x, fabsf(r1.x + v.x), acc1);
        acc2 = fmaf(w.x, fabsf(r2.x + v.x), acc2);
        acc3 = fmaf(w.x, fabsf(r3.x + v.x), acc3);
        acc0 = fmaf(w.y, fabsf(r0.y + v.y), acc0);
        acc1 = fmaf(w.y, fabsf(r1.y + v.y), acc1);
        acc2 = fmaf(w.y, fabsf(r2.y + v.y), acc2);
        acc3 = fmaf(w.y, fabsf(r3.y + v.y), acc3);
        acc0 = fmaf(w.z, fabsf(r0.z + v.z), acc0);
        acc1 = fmaf(w.z, fabsf(r1.z + v.z), acc1);
        acc2 = fmaf(w.z, fabsf(r2.z + v.z), acc2);
        acc3 = fmaf(w.z, fabsf(r3.z + v.z), acc3);
        acc0 = fmaf(w.w, fabsf(r0.w + v.w), acc0);
        acc1 = fmaf(w.w, fabsf(r1.w + v.w), acc1);
        acc2 = fmaf(w.w, fabsf(r2.w + v.w), acc2);
        acc3 = fmaf(w.w, fabsf(r3.w + v.w), acc3);
    }

    float sc[4];
    sc[0] = acc0 + av[n0]     + cm;
    sc[1] = acc1 + av[n0 + 1] + cm;
    sc[2] = acc2 + av[n0 + 2] + cm;
    sc[3] = acc3 + av[n0 + 3] + cm;

    // ---- block-local softmax over the 1024 columns, 4 rows ----
    __shared__ float rmax[4][16], rsum[4][16];
    const int wid = tid >> 6, lane = tid & 63;

    #pragma unroll
    for (int n = 0; n < 4; ++n) {
        float mx = sc[n];
        #pragma unroll
        for (int off = 32; off >= 1; off >>= 1)
            mx = fmaxf(mx, __shfl_xor(mx, off, 64));
        if (lane == 0) rmax[n][wid] = mx;
    }
    __syncthreads();

    float ex[4];
    #pragma unroll
    for (int n = 0; n < 4; ++n) {
        float mx = rmax[n][0];
        #pragma unroll
        for (int k = 1; k < 16; ++k) mx = fmaxf(mx, rmax[n][k]);
        float e = expf(sc[n] - mx);
        ex[n] = e;
        float s = e;
        #pragma unroll
        for (int off = 32; off >= 1; off >>= 1) s += __shfl_xor(s, off, 64);
        if (lane == 0) rsum[n][wid] = s;
    }
    __syncthreads();

    #pragma unroll
    for (int n = 0; n < 4; ++n) {
        float s = rsum[n][0];
        #pragma unroll
        for (int k = 1; k < 16; ++k) s += rsum[n][k];
        out[(n0 + n) * NTK + tid] = ex[n] * (1.0f / s);
    }
}

extern "C" void kernel_launch(void* const* d_in, const int* in_sizes, int n_in,
                              void* d_out, int out_size, void* d_ws, size_t ws_size,
                              hipStream_t stream)
{
    const float* xr  = (const float*)d_in[0];
    const float* xt  = (const float*)d_in[1];
    // d_in[2]=edge_index, [3]=edge_attr, [4..7]=We1,be1,We2,be2 : provably dead
    const float* Wv1 = (const float*)d_in[8];
    const float* bv1 = (const float*)d_in[9];
    const float* Wv2 = (const float*)d_in[10];
    const float* bv2 = (const float*)d_in[11];
    const float* Wm1 = (const float*)d_in[12];
    const float* bm1 = (const float*)d_in[13];
    const float* Wm2 = (const float*)d_in[14];
    const float* bm2 = (const float*)d_in[15];

    float* ws    = (float*)d_ws;
    float* HR    = ws;
    float* HTBt4 = ws + 65536;
    float* av    = ws + 196608;
    float* cv    = ws + 197120;
    float* wbv   = ws + 198144;
    float* out   = (float*)d_out;

    hipLaunchKernelGGL(prep_kernel, dim3(128), dim3(256), 0, stream,
                       xr, xt, Wv1, bv1, Wv2, bv2, Wm1, bm1, Wm2, bm2,
                       HR, HTBt4, av, cv, wbv);
    hipLaunchKernelGGL(score_softmax_kernel, dim3(128), dim3(1024), 0, stream,
                       HR, HTBt4, av, cv, wbv, out);
}

// Round 15
// 22.482 us; speedup vs baseline: 2.7538x; 1.5139x over previous
//
#include <hip/hip_runtime.h>

// Problem constants (from reference)
#define NRB 512
#define NTK 1024
#define DD  64
#define GHH 128

// Dead dataflow: tgt = edge_index[1]+512 in [512,1536) but robot_msgs =
// agg[:512] -> all-zero => edge MLP + segment_sum dead. lrelu(x) =
// 0.55x + 0.45|x| factors score into a[n] + c[m] + sum_h wb[h]*|HR+HTB|.
//
// FINAL: byte-identical restore of R9, the measured optimum (22.58us).
// Search history: R2 grid.sync ~60us/sync -> kernel boundaries mandatory.
// R3 256-VGPR latency-bound. R4 transpose for coalescing. R5 reg-array
// staging spills to scratch. R9 all-b128 prep + f4 score = best. R10/R11
// (MLP fusion into score, 2 ways), R12 (wb-sign split), R14 (Tn=4) all
// regressed. Score time invariant across 5 instruction mixes => bounded by
// fixed latency/ramp structure at 1 block/CU + the mandatory kernel
// boundary, not by issue count or stream BW at this size.

// Workspace layout (floats):
//   HR    [512][128]     @ 0        (row-major)
//   HTBt4 [32][1024][4]  @ 65536    (h-interleaved transpose, incl bm1)
//   a     [512]          @ 196608
//   c     [1024]         @ 197120
//   wb    [128]          @ 198144   (0.45 * Wm2)

// ---------------------------------------------------------------------------
// Kernel A: prep. 256 blocks x 256 threads.
// Blocks 0..127: robot path, 4 robots -> HR rows + a[n].
// Blocks 128..255: task path, 8 tasks -> HTBt4 + c[m]; block 128 wb.
// lds_w[i][132] row-major: col-i b128 read = banks 4i%32..+3; staged via
// coalesced global f4 -> single LDS f4 store.
// ---------------------------------------------------------------------------
__global__ __launch_bounds__(256) void prep_kernel(
    const float* __restrict__ xr, const float* __restrict__ xt,
    const float* __restrict__ Wv1, const float* __restrict__ bv1,
    const float* __restrict__ Wv2, const float* __restrict__ bv2,
    const float* __restrict__ Wm1, const float* __restrict__ bm1,
    const float* __restrict__ Wm2, const float* __restrict__ bm2,
    float* __restrict__ HR, float* __restrict__ HTBt4,
    float* __restrict__ av, float* __restrict__ cv, float* __restrict__ wbv)
{
    const int t = threadIdx.x;   // 0..255
    const int b = blockIdx.x;    // 0..255
    const int i = t & 127;       // output neuron (column)
    const int g = t >> 7;        // row-group 0/1

    __shared__ float lds_w[128 * 132];   // row-major weights, stride 132
    __shared__ float xs[8 * 64];         // input rows (flat)
    __shared__ float sA[4 * 132];        // h1 (robot)
    __shared__ float sB[4 * 132];        // h  (robot)
    __shared__ float sT[8 * 132];        // task pre-transpose
    __shared__ float sR[8 * 132];        // reduction scratch

    float4* Lw = reinterpret_cast<float4*>(lds_w);

    if (b < 128) {
        // ================= robot path: rows r0..r0+3 =================
        const int r0 = b * 4;
        xs[t] = xr[r0 * DD + t];                     // 256 floats, coalesced

        // stage W1 = Wv1[:,128:192]: 2048 f4, 1 load + 1 store each
        {
            const float4* W = reinterpret_cast<const float4*>(Wv1);
            #pragma unroll
            for (int j = 0; j < 8; ++j) {
                const int e = t + 256 * j;           // 0..2047
                const int row = e >> 4, c4 = e & 15;
                Lw[row * 33 + c4] = W[row * 48 + 32 + c4];
            }
        }
        __syncthreads();

        // phase 1: h1 = lrelu(x @ W1^T + bv1), rows 2g,2g+1, col i
        {
            float a0 = bv1[i], a1 = a0;
            const float4* w4 = Lw + i * 33;
            const float4* x0 = reinterpret_cast<const float4*>(xs + (2*g)*64);
            const float4* x1 = reinterpret_cast<const float4*>(xs + (2*g+1)*64);
            #pragma unroll
            for (int k = 0; k < 16; ++k) {
                const float4 w = w4[k];
                const float4 p = x0[k];
                const float4 q = x1[k];
                a0 = fmaf(w.x, p.x, a0); a1 = fmaf(w.x, q.x, a1);
                a0 = fmaf(w.y, p.y, a0); a1 = fmaf(w.y, q.y, a1);
                a0 = fmaf(w.z, p.z, a0); a1 = fmaf(w.z, q.z, a1);
                a0 = fmaf(w.w, p.w, a0); a1 = fmaf(w.w, q.w, a1);
            }
            sA[(2*g)*132 + i]   = (a0 >= 0.f) ? a0 : 0.1f * a0;
            sA[(2*g+1)*132 + i] = (a1 >= 0.f) ? a1 : 0.1f * a1;
        }
        __syncthreads();

        // stage W2 = Wv2 [128][128]: 4096 f4
        {
            const float4* W = reinterpret_cast<const float4*>(Wv2);
            #pragma unroll
            for (int j = 0; j < 16; ++j) {
                const int e = t + 256 * j;           // 0..4095
                const int row = e >> 5, c4 = e & 31;
                Lw[row * 33 + c4] = W[row * 32 + c4];
            }
        }
        __syncthreads();

        // phase 2: h = h1 @ W2^T + bv2
        {
            float a0 = bv2[i], a1 = a0;
            const float4* w4 = Lw + i * 33;
            const float4* h0 = reinterpret_cast<const float4*>(sA + (2*g)*132);
            const float4* h1 = reinterpret_cast<const float4*>(sA + (2*g+1)*132);
            #pragma unroll 8
            for (int k = 0; k < 32; ++k) {
                const float4 w = w4[k];
                const float4 p = h0[k];
                const float4 q = h1[k];
                a0 = fmaf(w.x, p.x, a0); a1 = fmaf(w.x, q.x, a1);
                a0 = fmaf(w.y, p.y, a0); a1 = fmaf(w.y, q.y, a1);
                a0 = fmaf(w.z, p.z, a0); a1 = fmaf(w.z, q.z, a1);
                a0 = fmaf(w.w, p.w, a0); a1 = fmaf(w.w, q.w, a1);
            }
            sB[(2*g)*132 + i]   = a0;
            sB[(2*g+1)*132 + i] = a1;
        }
        __syncthreads();

        // stage W3 = Wm1[:, :128]: 4096 f4 (row stride 192 -> 48 f4)
        {
            const float4* W = reinterpret_cast<const float4*>(Wm1);
            #pragma unroll
            for (int j = 0; j < 16; ++j) {
                const int e = t + 256 * j;
                const int row = e >> 5, c4 = e & 31;
                Lw[row * 33 + c4] = W[row * 48 + c4];
            }
        }
        __syncthreads();

        // phase 3: hr = h @ W3^T; HR write + a-partials
        {
            const float wm2 = Wm2[i];
            float a0 = 0.f, a1 = 0.f;
            const float4* w4 = Lw + i * 33;
            const float4* h0 = reinterpret_cast<const float4*>(sB + (2*g)*132);
            const float4* h1 = reinterpret_cast<const float4*>(sB + (2*g+1)*132);
            #pragma unroll 8
            for (int k = 0; k < 32; ++k) {
                const float4 w = w4[k];
                const float4 p = h0[k];
                const float4 q = h1[k];
                a0 = fmaf(w.x, p.x, a0); a1 = fmaf(w.x, q.x, a1);
                a0 = fmaf(w.y, p.y, a0); a1 = fmaf(w.y, q.y, a1);
                a0 = fmaf(w.z, p.z, a0); a1 = fmaf(w.z, q.z, a1);
                a0 = fmaf(w.w, p.w, a0); a1 = fmaf(w.w, q.w, a1);
            }
            HR[(r0 + 2*g) * GHH + i]     = a0;       // coalesced
            HR[(r0 + 2*g + 1) * GHH + i] = a1;
            sR[(2*g)*132 + i]   = wm2 * a0;
            sR[(2*g+1)*132 + i] = wm2 * a1;
        }
        __syncthreads();

        // a[n] = 0.55 * sum_i sR[n][i];  one wave per row
        {
            const int row = t >> 6, c = t & 63;
            float s = sR[row*132 + c] + sR[row*132 + c + 64];
            #pragma unroll
            for (int off = 32; off >= 1; off >>= 1)
                s += __shfl_xor(s, off, 64);
            if (c == 0) av[r0 + row] = 0.55f * s;
        }
    } else {
        // ================= task path: tasks t0..t0+7 =================
        const int t0 = (b - 128) * 8;
        xs[t]       = xt[t0 * DD + t];
        xs[256 + t] = xt[t0 * DD + 256 + t];

        // stage Wt = Wm1[:,128:192]: 2048 f4
        {
            const float4* W = reinterpret_cast<const float4*>(Wm1);
            #pragma unroll
            for (int j = 0; j < 8; ++j) {
                const int e = t + 256 * j;
                const int row = e >> 4, c4 = e & 15;
                Lw[row * 33 + c4] = W[row * 48 + 32 + c4];
            }
        }
        __syncthreads();

        // rows 4g..4g+3: htb = x_task @ Wt^T + bm1
        {
            const float bb  = bm1[i];
            const float wm2 = Wm2[i];
            float a0 = bb, a1 = bb, a2 = bb, a3 = bb;
            const float4* w4 = Lw + i * 33;
            const float4* x0 = reinterpret_cast<const float4*>(xs + (4*g)*64);
            const float4* x1 = reinterpret_cast<const float4*>(xs + (4*g+1)*64);
            const float4* x2 = reinterpret_cast<const float4*>(xs + (4*g+2)*64);
            const float4* x3 = reinterpret_cast<const float4*>(xs + (4*g+3)*64);
            #pragma unroll
            for (int k = 0; k < 16; ++k) {
                const float4 w = w4[k];
                const float4 p0 = x0[k], p1 = x1[k], p2 = x2[k], p3 = x3[k];
                a0 = fmaf(w.x, p0.x, a0); a1 = fmaf(w.x, p1.x, a1);
                a2 = fmaf(w.x, p2.x, a2); a3 = fmaf(w.x, p3.x, a3);
                a0 = fmaf(w.y, p0.y, a0); a1 = fmaf(w.y, p1.y, a1);
                a2 = fmaf(w.y, p2.y, a2); a3 = fmaf(w.y, p3.y, a3);
                a0 = fmaf(w.z, p0.z, a0); a1 = fmaf(w.z, p1.z, a1);
                a2 = fmaf(w.z, p2.z, a2); a3 = fmaf(w.z, p3.z, a3);
                a0 = fmaf(w.w, p0.w, a0); a1 = fmaf(w.w, p1.w, a1);
                a2 = fmaf(w.w, p2.w, a2); a3 = fmaf(w.w, p3.w, a3);
            }
            sT[(4*g)*132 + i]   = a0;  sR[(4*g)*132 + i]   = wm2 * a0;
            sT[(4*g+1)*132 + i] = a1;  sR[(4*g+1)*132 + i] = wm2 * a1;
            sT[(4*g+2)*132 + i] = a2;  sR[(4*g+2)*132 + i] = wm2 * a2;
            sT[(4*g+3)*132 + i] = a3;  sR[(4*g+3)*132 + i] = wm2 * a3;
        }
        __syncthreads();

        // interleaved transposed write: HTBt4[h4][t0+tk] = htb[tk][4h4..4h4+3]
        {
            const int h4 = t >> 3, tk = t & 7;
            float4 v;
            v.x = sT[tk*132 + 4*h4 + 0];
            v.y = sT[tk*132 + 4*h4 + 1];
            v.z = sT[tk*132 + 4*h4 + 2];
            v.w = sT[tk*132 + 4*h4 + 3];
            reinterpret_cast<float4*>(HTBt4)[h4 * NTK + t0 + tk] = v;
        }

        // c[m] = 0.55 * sum_i sR[m][i] + bm2;  half-wave per task
        {
            const int row = t >> 5, c = t & 31;
            float s = sR[row*132 + c]      + sR[row*132 + c + 32]
                    + sR[row*132 + c + 64] + sR[row*132 + c + 96];
            #pragma unroll
            for (int off = 16; off >= 1; off >>= 1)
                s += __shfl_xor(s, off, 32);
            if (c == 0) cv[t0 + row] = 0.55f * s + bm2[0];
        }
        if (b == 128 && t < GHH) wbv[t] = 0.45f * Wm2[t];
    }
}

// ---------------------------------------------------------------------------
// Kernel B: fused score + softmax. 256 blocks x 1024 threads (4 waves/SIMD).
// Block b owns rows n0=2b,2b+1; thread tid owns column m=tid.
// Per h4 (32 iters): 1 coalesced dwordx4 of HTBt4[h4][tid] + 3 UNIFORM
// global f4 loads (wb4/hr0/hr1) + 16 VALU. Then block softmax, coalesced
// store. No register arrays (R5 lesson).
// ---------------------------------------------------------------------------
__global__ __launch_bounds__(1024) void score_softmax_kernel(
    const float* __restrict__ HR, const float* __restrict__ HTBt4,
    const float* __restrict__ av, const float* __restrict__ cv,
    const float* __restrict__ wbv, float* __restrict__ out)
{
    const int b   = blockIdx.x;     // 0..255
    const int tid = threadIdx.x;    // 0..1023 == m
    const int n0  = b * 2;

    const float4* tb  = reinterpret_cast<const float4*>(HTBt4) + tid;
    const float4* hrA = reinterpret_cast<const float4*>(HR + n0 * GHH);
    const float4* hrB = reinterpret_cast<const float4*>(HR + (n0 + 1) * GHH);
    const float4* wb4 = reinterpret_cast<const float4*>(wbv);

    float acc0 = 0.f, acc1 = 0.f;

    #pragma unroll 4
    for (int h4 = 0; h4 < 32; ++h4) {
        const float4 v  = tb[h4 << 10];     // coalesced dwordx4
        const float4 w  = wb4[h4];          // uniform
        const float4 r0 = hrA[h4];          // uniform
        const float4 r1 = hrB[h4];          // uniform
        acc0 = fmaf(w.x, fabsf(r0.x + v.x), acc0);
        acc1 = fmaf(w.x, fabsf(r1.x + v.x), acc1);
        acc0 = fmaf(w.y, fabsf(r0.y + v.y), acc0);
        acc1 = fmaf(w.y, fabsf(r1.y + v.y), acc1);
        acc0 = fmaf(w.z, fabsf(r0.z + v.z), acc0);
        acc1 = fmaf(w.z, fabsf(r1.z + v.z), acc1);
        acc0 = fmaf(w.w, fabsf(r0.w + v.w), acc0);
        acc1 = fmaf(w.w, fabsf(r1.w + v.w), acc1);
    }

    const float cm = cv[tid];
    float sc[2];
    sc[0] = acc0 + av[n0]     + cm;
    sc[1] = acc1 + av[n0 + 1] + cm;

    // ---- block-local softmax over the 1024 columns, both rows ----
    __shared__ float rmax[2][16], rsum[2][16];
    const int wid = tid >> 6, lane = tid & 63;

    #pragma unroll
    for (int n = 0; n < 2; ++n) {
        float mx = sc[n];
        #pragma unroll
        for (int off = 32; off >= 1; off >>= 1)
            mx = fmaxf(mx, __shfl_xor(mx, off, 64));
        if (lane == 0) rmax[n][wid] = mx;
    }
    __syncthreads();

    float ex[2];
    #pragma unroll
    for (int n = 0; n < 2; ++n) {
        float mx = rmax[n][0];
        #pragma unroll
        for (int k = 1; k < 16; ++k) mx = fmaxf(mx, rmax[n][k]);
        float e = expf(sc[n] - mx);
        ex[n] = e;
        float s = e;
        #pragma unroll
        for (int off = 32; off >= 1; off >>= 1) s += __shfl_xor(s, off, 64);
        if (lane == 0) rsum[n][wid] = s;
    }
    __syncthreads();

    #pragma unroll
    for (int n = 0; n < 2; ++n) {
        float s = rsum[n][0];
        #pragma unroll
        for (int k = 1; k < 16; ++k) s += rsum[n][k];
        out[(n0 + n) * NTK + tid] = ex[n] * (1.0f / s);
    }
}

extern "C" void kernel_launch(void* const* d_in, const int* in_sizes, int n_in,
                              void* d_out, int out_size, void* d_ws, size_t ws_size,
                              hipStream_t stream)
{
    const float* xr  = (const float*)d_in[0];
    const float* xt  = (const float*)d_in[1];
    // d_in[2]=edge_index, [3]=edge_attr, [4..7]=We1,be1,We2,be2 : provably dead
    const float* Wv1 = (const float*)d_in[8];
    const float* bv1 = (const float*)d_in[9];
    const float* Wv2 = (const float*)d_in[10];
    const float* bv2 = (const float*)d_in[11];
    const float* Wm1 = (const float*)d_in[12];
    const float* bm1 = (const float*)d_in[13];
    const float* Wm2 = (const float*)d_in[14];
    const float* bm2 = (const float*)d_in[15];

    float* ws    = (float*)d_ws;
    float* HR    = ws;
    float* HTBt4 = ws + 65536;
    float* av    = ws + 196608;
    float* cv    = ws + 197120;
    float* wbv   = ws + 198144;
    float* out   = (float*)d_out;

    hipLaunchKernelGGL(prep_kernel, dim3(256), dim3(256), 0, stream,
                       xr, xt, Wv1, bv1, Wv2, bv2, Wm1, bm1, Wm2, bm2,
                       HR, HTBt4, av, cv, wbv);
    hipLaunchKernelGGL(score_softmax_kernel, dim3(256), dim3(1024), 0, stream,
                       HR, HTBt4, av, cv, wbv, out);
}